// Round 12
// baseline (9387.269 us; speedup 1.0000x reference)
//
#include <hip/hip_runtime.h>
#include <hip/hip_bf16.h>

typedef __attribute__((ext_vector_type(8))) short short8;
typedef __attribute__((ext_vector_type(4))) float f32x4;
typedef __attribute__((ext_vector_type(2))) float f32x2;
typedef unsigned short u16;
typedef unsigned int u32;
typedef unsigned long long u64;

#define DEV __device__ __forceinline__

// ---- problem dims ----
static constexpr int Hd    = 256;
static constexpr int Bb    = 32;
static constexpr int Pp    = 400;
static constexpr int Qq    = 40;
static constexpr int NROWS = Pp * Bb + Qq * Bb;   // 14080
static constexpr int PROBE_MAGIC = 1234567;
static constexpr int NPROBE = 14;

// ---- numeric helpers ----
DEV float bf2f(u16 u) { u32 i = ((u32)u) << 16; float f; __builtin_memcpy(&f, &i, 4); return f; }
DEV u16 f2bf(float f) { u32 i; __builtin_memcpy(&i, &f, 4); i += 0x7FFFu + ((i >> 16) & 1u); return (u16)(i >> 16); }
DEV float sigf(float x) { return __builtin_amdgcn_rcpf(1.f + __expf(-x)); }
DEV float tanhf_(float x) {
  float ax = __builtin_fabsf(x);
  float t = __expf(2.f * ax);
  float r = 1.f - 2.f * __builtin_amdgcn_rcpf(t + 1.f);
  return x < 0.f ? -r : r;
}
DEV f32x4 mfma32(short8 a, short8 b, f32x4 c) {
  return __builtin_amdgcn_mfma_f32_16x16x32_bf16(a, b, c, 0, 0, 0);
}
DEV short8 zero8() { short8 z = {0,0,0,0,0,0,0,0}; return z; }
// fragment-tiled B load: one contiguous 1KB per wave
DEV short8 ldtile(const u16* base, int tile, int lane) {
  return *(const short8*)(base + ((size_t)tile * 64 + lane) * 8);
}

// cross-block WRITES: relaxed agent atomics (bypass caches -> land at coherence point).
DEV void ast64(u64* p, u64 v) { __hip_atomic_store(p, v, __ATOMIC_RELAXED, __HIP_MEMORY_SCOPE_AGENT); }
// lane-quad pack: each lane holds 1 bf16 (consecutive lanes = consecutive elements);
// lane%4==0 stores 8B covering 4 lanes' values.
DEV void quad_store(u16* base_even, u16 mine, int lane) {
  u32 p01 = (u32)mine | ((u32)(u16)__shfl_xor((int)mine, 1, 64) << 16);
  u32 p23 = (u32)__shfl_xor((int)p01, 2, 64);
  if (!(lane & 3)) ast64((u64*)base_even, (u64)p01 | ((u64)p23 << 32));
}
// pair-pack for threads already holding 2 bf16 (packed u32), partner lane holds next 2.
DEV void pair_store(u16* base_even, u32 mine2, int lane) {
  u32 other = (u32)__shfl_xor((int)mine2, 1, 64);
  if (!(lane & 1)) ast64((u64*)base_even, (u64)mine2 | ((u64)other << 32));
}

struct KArgs {
  const int *pids, *qids, *plen, *qlen;
  const float *embedF, *preWihF, *preWhhF, *preBF, *WqF, *WpF, *bpF, *WhF,
              *walphaF, *balphaF, *mWihF, *mWhhF, *mBF, *WmF, *WaF, *baF,
              *wbetaF, *bbetaF, *pWihF, *pWhhF, *pBF;
  int* bar;   // [grp*64 .. grp*64+16): flags; [768..]: probes
  u16 *WqT, *WpT, *WmT, *WihP, *Xpad, *preX, *Hp, *Hq, *Hrb, *wqR, *wHr, *haB,
      *attQb, *pWihB, *pWhhB, *mWxb, *WhTb, *preWhT, *xW;
  float *hpWp, *attM, *scores, *aWa, *gatesW;
  float* out;   // FLOAT32 output
};

DEV void probe_mark(int* bar, int idx) {
  if (blockIdx.x == 0 && threadIdx.x == 0)
    __hip_atomic_store(bar + 768 + idx, PROBE_MAGIC, __ATOMIC_RELEASE, __HIP_MEMORY_SCOPE_AGENT);
}

// ---- FULLY RELAXED flag-array barrier: no release, no acquire, no RMW.
// Ordering: __syncthreads() drains vmcnt (compiler-emitted) -> prior sc1 bypass
// stores are at the coherence point before the flag store issues. Readers use
// cached loads only on first-touch addresses (never stale) or bypass atomics.
DEV void barn(int* flagbase, int gi, int gen) {
  __syncthreads();
  if (threadIdx.x == 0)
    __hip_atomic_store((u32*)flagbase + gi, (u32)gen, __ATOMIC_RELAXED, __HIP_MEMORY_SCOPE_AGENT);
  if (threadIdx.x < 16) {
    while (__hip_atomic_load((u32*)flagbase + threadIdx.x, __ATOMIC_RELAXED, __HIP_MEMORY_SCOPE_AGENT) < (u32)gen)
      __builtin_amdgcn_s_sleep(2);
  }
  __syncthreads();
}

// ======================= k_prep =======================
__global__ __launch_bounds__(256) void k_prep(KArgs A) {
  const int gtid = blockIdx.x * 256 + threadIdx.x;
  const int GS = 256 * 256;
  for (int idx = gtid; idx < 1024 * 160; idx += GS) {
    int row = idx / 160, cd = idx - row * 160;
    u32 v = 0;
    if (cd < 150) {
      f32x2 e2 = *(const f32x2*)(A.preWihF + (size_t)row * 300 + cd * 2);
      v = (u32)f2bf(e2[0]) | ((u32)f2bf(e2[1]) << 16);
    }
    *(u32*)(A.WihP + (size_t)row * 320 + cd * 2) = v;
  }
  for (int idx = gtid; idx < NROWS * 160; idx += GS) {
    int row = idx / 160, cd = idx - row * 160;
    int id = (row < Pp * Bb) ? A.pids[row] : A.qids[row - Pp * Bb];
    u32 v = 0;
    if (cd < 150) {
      f32x2 e2 = *(const f32x2*)(A.embedF + (size_t)id * 300 + cd * 2);
      v = (u32)f2bf(e2[0]) | ((u32)f2bf(e2[1]) << 16);
    }
    *(u32*)(A.Xpad + (size_t)row * 320 + cd * 2) = v;
  }
  for (int idx = gtid; idx < 65536; idx += GS) {
    int r = idx >> 8, c = idx & 255;
    A.WqT[idx]  = f2bf(A.WqF[c * 256 + r]);
    A.WpT[idx]  = f2bf(A.WpF[c * 256 + r]);
    A.WhTb[idx] = f2bf(A.WhF[c * 256 + r]);   // WhT[n][k] = Wh[k][n]
  }
  for (int idx = gtid; idx < 131072; idx += GS) {
    int r = idx >> 9, c = idx & 511;
    A.WmT[idx] = f2bf(A.WmF[c * 256 + r]);
  }
  for (int idx = gtid; idx < 1024 * 256; idx += GS) {   // mWih first-half (hp part)
    int n = idx >> 8, k = idx & 255;
    A.mWxb[idx] = f2bf(A.mWihF[(size_t)n * 512 + k]);
  }
  // fragment-tiled preWhh (rows i,f,g) for the barrier-free prescan
  for (int idx = gtid; idx < 48 * 8 * 512; idx += GS) {
    int e = idx & 7, l = (idx >> 3) & 63, tk = idx >> 9;
    int nt = tk >> 3, kt = tk & 7;
    int n = nt * 16 + (l & 15), k = kt * 32 + (l >> 4) * 8 + e;
    A.preWhT[idx] = f2bf(A.preWhhF[(size_t)n * 256 + k]);
  }
  for (int idx = gtid; idx < 524288 + 262144; idx += GS) {
    if (idx < 524288) A.pWihB[idx] = f2bf(A.pWihF[idx]);
    else              A.pWhhB[idx - 524288] = f2bf(A.pWhhF[idx - 524288]);
  }
  if (gtid < 32 * 256) {
    A.aWa[gtid] = A.baF[gtid & 255];
    A.haB[gtid] = 0;
  }
  probe_mark(A.bar, 0);
}

// ======================= k_gemm =======================
struct GemmArgs { const u16* Ag; int lda; const u16* Bg; int ldb; int Mt64, Nt64, nk; float* Cf; u16* Cb; int ldc; int* bar; int probe; };

__global__ __launch_bounds__(512) void k_gemm(GemmArgs g) {
  const int tid = threadIdx.x, lane = tid & 63;
  const int r16 = lane & 15, kl = (lane >> 4) * 8;
  const int ntile = g.Mt64 * g.Nt64;
  const int stride = gridDim.x * 8;
  for (int tix = blockIdx.x * 8 + (tid >> 6); tix < ntile; tix += stride) {
    int m0 = (tix / g.Nt64) * 64, n0 = (tix % g.Nt64) * 64;
    f32x4 acc[4][4] = {};
    for (int kb = 0; kb < g.nk; ++kb) {
      int k0 = kb * 32 + kl;
      short8 a[4], b[4];
#pragma unroll
      for (int i = 0; i < 4; ++i) {
        a[i] = *(const short8*)(g.Ag + (size_t)(m0 + i * 16 + r16) * g.lda + k0);
        b[i] = *(const short8*)(g.Bg + (size_t)(n0 + i * 16 + r16) * g.ldb + k0);
      }
#pragma unroll
      for (int mi = 0; mi < 4; ++mi)
#pragma unroll
        for (int ni = 0; ni < 4; ++ni) acc[mi][ni] = mfma32(a[mi], b[ni], acc[mi][ni]);
    }
#pragma unroll
    for (int mi = 0; mi < 4; ++mi)
#pragma unroll
      for (int ni = 0; ni < 4; ++ni)
#pragma unroll
        for (int j = 0; j < 4; ++j) {
          int r = m0 + mi * 16 + (lane >> 4) * 4 + j, cc = n0 + ni * 16 + r16;
          if (g.Cf) g.Cf[(size_t)r * g.ldc + cc] = acc[mi][ni][j];
          else      g.Cb[(size_t)r * g.ldc + cc] = f2bf(acc[mi][ni][j]);
        }
  }
  probe_mark(g.bar, g.probe);
}

// ======================= k_prescan: per-chain, ZERO barriers (R10/R11, validated) =======================
__global__ __launch_bounds__(512, 1) void k_prescan(KArgs A) {
  __shared__ __align__(16) unsigned char sm[24576];
  u16*   HF  = (u16*)sm;                // [4][264]
  float* CS  = (float*)(sm + 2176);     // [4][256]
  float* PRE = (float*)(sm + 6784);     // [4][776]
  float* PBL = (float*)(sm + 19648);    // [768]
  const int blk = blockIdx.x;
  const int isQ = blk >> 3;
  const int c0  = (blk & 7) * 4;
  const int steps = isQ ? Qq : Pp;
  const int* lens = isQ ? A.qlen : A.plen;
  u16* Hs = isQ ? A.Hq : A.Hp;
  const int xoff = isQ ? Pp * Bb : 0;
  const int tid = threadIdx.x, lane = tid & 63, wv = tid >> 6;
  const int r16 = lane & 15, kl = (lane >> 4) * 8;

  for (int idx = tid; idx < 768; idx += 512) PBL[idx] = A.preBF[idx];
  for (int idx = tid; idx < 4 * 264; idx += 512) HF[idx] = 0;
  for (int idx = tid; idx < 4 * 256; idx += 512) CS[idx] = 0.f;
  __syncthreads();

  const int cC = tid >> 7, hh = (tid & 127) * 2;
  const int bC = c0 + cC;
  const int lenC = lens[bC];

#pragma unroll 1
  for (int t = 0; t < steps; ++t) {
    short8 afr[8];
#pragma unroll
    for (int kt = 0; kt < 8; ++kt)
      afr[kt] = (r16 < 4) ? *(const short8*)(HF + r16 * 264 + kt * 32 + kl) : zero8();
#pragma unroll
    for (int i = 0; i < 6; ++i) {
      int nt = wv * 6 + i;
      short8 bf[8];
#pragma unroll
      for (int kt = 0; kt < 8; ++kt) bf[kt] = ldtile(A.preWhT, nt * 8 + kt, lane);
      f32x4 acc = {0.f, 0.f, 0.f, 0.f};
#pragma unroll
      for (int kt = 0; kt < 8; ++kt) acc = mfma32(afr[kt], bf[kt], acc);
      if ((lane >> 4) == 0) {
#pragma unroll
        for (int j = 0; j < 4; ++j) PRE[j * 776 + nt * 16 + r16] = acc[j];
      }
    }
    __syncthreads();
    {
      size_t xr = (size_t)(xoff + t * 32 + bC) * 1024;
      u32 x0 = *(const u32*)(A.preX + xr + hh);
      u32 x1 = *(const u32*)(A.preX + xr + 256 + hh);
      u32 x2 = *(const u32*)(A.preX + xr + 512 + hh);
      u16 hb[2];
#pragma unroll
      for (int u = 0; u < 2; ++u) {
        int h = hh + u;
        float xi = bf2f(u ? (u16)(x0 >> 16) : (u16)x0);
        float xf = bf2f(u ? (u16)(x1 >> 16) : (u16)x1);
        float xg = bf2f(u ? (u16)(x2 >> 16) : (u16)x2);
        float ip = PRE[cC * 776 + h]       + xi + PBL[h];
        float fp = PRE[cC * 776 + 256 + h] + xf + PBL[256 + h];
        float gp = PRE[cC * 776 + 512 + h] + xg + PBL[512 + h];
        float c2 = sigf(fp) * CS[cC * 256 + h] + sigf(ip) * tanhf_(gp);
        float mt = (t < lenC) ? 1.f : 0.f;
        float h2 = tanhf_(c2) * mt;
        CS[cC * 256 + h] = c2 * mt;
        hb[u] = f2bf(h2);
      }
      u32 pk = (u32)hb[0] | ((u32)hb[1] << 16);
      *(u32*)(HF + cC * 264 + hh) = pk;
      *(u32*)(Hs + (size_t)(t * 32 + bC) * 256 + hh) = pk;   // plain store; kernel-boundary coherence
    }
    __syncthreads();
  }
  probe_mark(A.bar, 2);
}

// ======================= k_match: sliced, relaxed-flag rendezvous (R8 structure) =======================
// 32 blocks: 0-15 fwd, 16-31 bwd; block gi owns hidden slice [gi*16,+16).
// e computed locally (WhTb L2-warm — no fences, caches stay hot); wq via 400-deep ring
// (first-touch cached reads); cross-block writes via 8B bypass atomics.
__global__ __launch_bounds__(512, 1) void k_match(KArgs A) {
  __shared__ __align__(16) unsigned char sm[81920];
  // [0, 65536): weight slice, 64 rows x 1024B (cols: [mWih_wq(256)|mWhh(256)]), swizzled
  float* PRE = (float*)(sm + 65536);      // [32][64]
  float* CL  = (float*)(sm + 73728);      // [32][16]
  float* EL  = (float*)(sm + 75776);      // [2][256]
  float* SL  = (float*)(sm + 77824);      // [2][40]
  float* AL  = (float*)(sm + 78336);      // [2][40]
  float* BPL = (float*)(sm + 78848);      // [256]
  float* WAL = (float*)(sm + 79872);      // [256]
  float* MBL = (float*)(sm + 80896);      // [64]

  const int blk = blockIdx.x;
  const int gi  = blk & 15;
  const int dir = blk >> 4;
  int* flags = A.bar + (2 + dir) * 64;
  const int tid = threadIdx.x, lane = tid & 63, wv = tid >> 6;
  const int r16 = lane & 15, kl = (lane >> 4) * 8;
  const int h0 = gi * 16;

  for (int idx = tid; idx < 64 * 512; idx += 512) {
    int row = idx >> 9, k = idx & 511;
    int gate = (row >> 4) * 256 + h0 + (row & 15);
    float v = (k < 256) ? A.mWihF[(size_t)gate * 512 + 256 + k]
                        : A.mWhhF[(size_t)gate * 256 + (k - 256)];
    int byte = row * 1024 + ((2 * k) ^ ((row & 7) << 4));
    *(u16*)(sm + byte) = f2bf(v);
  }
  for (int idx = tid; idx < 32 * 16; idx += 512) CL[idx] = 0.f;
  if (tid < 256) { BPL[tid] = A.bpF[tid]; WAL[tid] = A.walphaF[tid]; }
  if (tid < 64) MBL[tid] = A.mBF[(tid >> 4) * 256 + h0 + (tid & 15)];
  __syncthreads();

  const float bAl = A.balphaF[0];
  const int cS = wv >> 2, bS = gi * 2 + cS, q4 = wv & 3;       // scores mapping
  const int cW = tid >> 8, hW = tid & 255, bW = gi * 2 + cW;   // wq mapping
  const int chainC = tid >> 4, hd = tid & 15;                  // cell mapping
  const int miG = wv >> 2, niG = wv & 3, chainG = miG * 16 + r16, rowG = niG * 16 + r16; // gates

  // ---- hoisted t-invariant register caches (attQ, Hq slices) ----
  float aq[10][4], hqv[40];
#pragma unroll
  for (int i = 0; i < 10; ++i)
#pragma unroll
    for (int j = 0; j < 4; ++j)
      aq[i][j] = bf2f(A.attQb[(size_t)((q4 + 4 * i) * 32 + bS) * 256 + lane + 64 * j]);
#pragma unroll
  for (int q = 0; q < 40; ++q)
    hqv[q] = bf2f(A.Hq[(size_t)(q * 32 + bW) * 256 + hW]);

  int gen = 0;
#pragma unroll 1
  for (int t = 0; t < Pp; ++t) {
    int p  = dir ? (Pp - 1 - t) : t;
    int pp = dir ? (p + 1) : (p - 1);

    // per-step prefetch (L2-warm; hides under barrier wait)
    float hw[4], xw4[4];
#pragma unroll
    for (int j = 0; j < 4; ++j)
      hw[j] = A.hpWp[(size_t)(p * 32 + bS) * 256 + lane + 64 * j];
#pragma unroll
    for (int g = 0; g < 4; ++g)
      xw4[g] = bf2f(A.xW[(size_t)(p * 32 + chainC) * 1024 + g * 256 + h0 + hd]);

    barn(flags, gi, ++gen);                 // h(t-1) landed at coherence point (first-touch reads)

    // ---- e = h_{t-1}[2 chains] @ Wh : local MFMA (WhTb cached/warm) ----
    if (t == 0) {
      EL[tid] = 0.f;
    } else {
      f32x4 acc0 = {0.f,0.f,0.f,0.f}, acc1 = {0.f,0.f,0.f,0.f};
#pragma unroll
      for (int kb = 0; kb < 8; ++kb) {
        int k0 = kb * 32 + kl;
        short8 a = zero8();
        if (r16 < 2)
          a = *(const short8*)(A.Hrb + (size_t)(pp * 32 + gi * 2 + r16) * 512 + dir * 256 + k0);
        short8 bA = *(const short8*)(A.WhTb + (size_t)(wv * 32 + r16) * 256 + k0);
        short8 bB = *(const short8*)(A.WhTb + (size_t)(wv * 32 + 16 + r16) * 256 + k0);
        acc0 = mfma32(a, bA, acc0);
        acc1 = mfma32(a, bB, acc1);
      }
      if ((lane >> 4) == 0) {
        EL[0 * 256 + wv * 32 + r16]      = acc0[0];
        EL[1 * 256 + wv * 32 + r16]      = acc0[1];
        EL[0 * 256 + wv * 32 + 16 + r16] = acc1[0];
        EL[1 * 256 + wv * 32 + 16 + r16] = acc1[1];
      }
    }
    __syncthreads();
    // ---- attention scores ----
    {
#pragma unroll
      for (int i = 0; i < 10; ++i) {
        int q = q4 + 4 * i;
        float s = 0.f;
#pragma unroll
        for (int j = 0; j < 4; ++j) {
          int h = lane + 64 * j;
          s += WAL[h] * tanhf_(aq[i][j] + hw[j] + BPL[h] + EL[cS * 256 + h]);
        }
#pragma unroll
        for (int off = 32; off; off >>= 1) s += __shfl_xor(s, off, 64);
        if (lane == 0) SL[cS * 40 + q] = s;
      }
    }
    __syncthreads();
    // ---- softmax over q ----
    if ((wv & 3) == 0) {
      int c = wv >> 2;
      float x = (lane < 40) ? (SL[c * 40 + lane] + bAl) : -3.4e38f;
      float m = x;
#pragma unroll
      for (int off = 32; off; off >>= 1) m = fmaxf(m, __shfl_xor(m, off, 64));
      float e = (lane < 40) ? __expf(x - m) : 0.f;
      float su = e;
#pragma unroll
      for (int off = 32; off; off >>= 1) su += __shfl_xor(su, off, 64);
      if (lane < 40) AL[c * 40 + lane] = e / su;
    }
    __syncthreads();
    // ---- wq -> ring slot t (8B bypass store) ----
    {
      float acc = 0.f;
#pragma unroll 8
      for (int q = 0; q < 40; ++q) acc += AL[cW * 40 + q] * hqv[q];
      float mt = (p < A.plen[bW]) ? 1.f : 0.f;
      u16 wb = f2bf(acc * mt);
      quad_store(A.wqR + (size_t)t * 16384 + (size_t)(dir * 32 + bW) * 256 + (hW & ~3), wb, lane);
    }
    // ---- gates part 1: h_{t-1} contribution (Hrb L1-hot from e-phase) ----
    f32x4 accG = {0.f, 0.f, 0.f, 0.f};
    if (t > 0) {
#pragma unroll
      for (int kb = 8; kb < 16; ++kb) {
        int k0 = kb * 32 + kl;
        short8 a = *(const short8*)(A.Hrb + (size_t)(pp * 32 + chainG) * 512 + dir * 256 + (k0 - 256));
        short8 b = *(const short8*)(sm + rowG * 1024 + ((2 * k0) ^ ((rowG & 7) << 4)));
        accG = mfma32(a, b, accG);
      }
    }
    barn(flags, gi, ++gen);                 // wq(t) landed

    // ---- gates part 2: wq contribution (ring slot t = first-touch cached read) ----
    {
      const u16* wqS = A.wqR + (size_t)t * 16384 + (size_t)(dir * 32 + chainG) * 256;
#pragma unroll
      for (int kb = 0; kb < 8; ++kb) {
        int k0 = kb * 32 + kl;
        short8 a = *(const short8*)(wqS + k0);
        short8 b = *(const short8*)(sm + rowG * 1024 + ((2 * k0) ^ ((rowG & 7) << 4)));
        accG = mfma32(a, b, accG);
      }
      int col = niG * 16 + r16;
#pragma unroll
      for (int j = 0; j < 4; ++j)
        PRE[(miG * 16 + (lane >> 4) * 4 + j) * 64 + col] = accG[j];
    }
    __syncthreads();
    // ---- cell elementwise ----
    {
      float ig = PRE[chainC * 64 + hd]      + MBL[hd]      + xw4[0];
      float fg = PRE[chainC * 64 + 16 + hd] + MBL[16 + hd] + xw4[1];
      float gg = PRE[chainC * 64 + 32 + hd] + MBL[32 + hd] + xw4[2];
      float og = PRE[chainC * 64 + 48 + hd] + MBL[48 + hd] + xw4[3];
      float c2 = sigf(fg) * CL[chainC * 16 + hd] + sigf(ig) * tanhf_(gg);
      float h2 = sigf(og) * tanhf_(c2);
      float mt = (p < A.plen[chainC]) ? 1.f : 0.f;
      c2 *= mt; h2 *= mt;
      CL[chainC * 16 + hd] = c2;
      u16 hb = f2bf(h2);
      quad_store(A.Hrb + (size_t)(p * 32 + chainC) * 512 + dir * 256 + h0 + (hd & ~3), hb, lane);
    }
  }
  probe_mark(A.bar, 6);
}

// ======================= pointer net =======================
__global__ __launch_bounds__(512) void k_scores(KArgs A, int probe) {
  const int blk = blockIdx.x, tid = threadIdx.x, lane = tid & 63, wv = tid >> 6;
  for (int j = wv; j < 50; j += 8) {
    int id = blk * 50 + j;
    int p = id >> 5, b = id & 31;
    float s = 0.f;
#pragma unroll
    for (int jj = 0; jj < 4; ++jj) {
      int h = lane + 64 * jj;
      s += A.wbetaF[h] * tanhf_(A.attM[(size_t)(p * 32 + b) * 256 + h] + A.aWa[b * 256 + h]);
    }
#pragma unroll
    for (int off = 32; off; off >>= 1) s += __shfl_xor(s, off, 64);
    if (lane == 0)
      A.scores[p * 32 + b] = (p < A.plen[b]) ? (s + A.bbetaF[0]) : -1e30f;
  }
  probe_mark(A.bar, probe);
}

__global__ __launch_bounds__(512) void k_soft(KArgs A, int k, int probe) {
  __shared__ __align__(16) unsigned char sm[2048];
  float* BL = (float*)sm;            // [400]
  float* RED = (float*)(sm + 1664);  // [16]
  const int b = blockIdx.x, tid = threadIdx.x, lane = tid & 63, wv = tid >> 6;
  float x = (tid < 400) ? A.scores[tid * 32 + b] : -3.4e38f;
  float m = x;
#pragma unroll
  for (int off = 32; off; off >>= 1) m = fmaxf(m, __shfl_xor(m, off, 64));
  if (lane == 0) RED[wv] = m;
  __syncthreads();
  if (tid == 0) {
    float mm = RED[0];
#pragma unroll
    for (int i = 1; i < 8; ++i) mm = fmaxf(mm, RED[i]);
    RED[0] = mm;
  }
  __syncthreads();
  float M = RED[0];
  float e = (tid < 400) ? __expf(x - M) : 0.f;
  float su = e;
#pragma unroll
  for (int off = 32; off; off >>= 1) su += __shfl_xor(su, off, 64);
  if (lane == 0) RED[8 + wv] = su;
  __syncthreads();
  if (tid == 0) {
    float ss = 0.f;
#pragma unroll
    for (int i = 0; i < 8; ++i) ss += RED[8 + i];
    RED[8] = ss;
  }
  __syncthreads();
  float SUM = RED[8];
  if (tid < 400) {
    float beta = (e / SUM) * ((tid < A.plen[b]) ? 1.f : 0.f);
    A.out[(size_t)(k * 32 + b) * 400 + tid] = beta;
    BL[tid] = beta;
  }
  if (k == 0) {
    __syncthreads();
    float acc = 0.f;
#pragma unroll 4
    for (int p = 0; p < 400; ++p) acc += BL[p] * bf2f(A.Hrb[(size_t)(p * 32 + b) * 512 + tid]);
    A.wHr[b * 512 + tid] = f2bf(acc);
  }
  probe_mark(A.bar, probe);
}

__global__ __launch_bounds__(128) void k_pgates(KArgs A) {
  const int blk = blockIdx.x, tid = threadIdx.x, lane = tid & 63, wv = tid >> 6;
  const int r16 = lane & 15, kl = (lane >> 4) * 8;
  const int g0 = blk * 16;
  const int mi = wv, chain = mi * 16 + r16;
  f32x4 acc = {0.f, 0.f, 0.f, 0.f};
#pragma unroll
  for (int kb = 0; kb < 24; ++kb) {
    int k0 = kb * 32 + kl;
    short8 a, b;
    if (kb < 16) {
      a = *(const short8*)(A.wHr + (size_t)chain * 512 + k0);
      b = *(const short8*)(A.pWihB + (size_t)(g0 + r16) * 512 + k0);
    } else {
      a = *(const short8*)(A.haB + (size_t)chain * 256 + (k0 - 512));
      b = *(const short8*)(A.pWhhB + (size_t)(g0 + r16) * 256 + (k0 - 512));
    }
    acc = mfma32(a, b, acc);
  }
#pragma unroll
  for (int j = 0; j < 4; ++j)
    A.gatesW[(size_t)(mi * 16 + (lane >> 4) * 4 + j) * 1024 + g0 + r16] = acc[j];
  probe_mark(A.bar, 10);
}

__global__ __launch_bounds__(256) void k_pcell(KArgs A) {
  __shared__ float HL[256];
  const int b = blockIdx.x, hd = threadIdx.x;
  {
    float ig = A.gatesW[(size_t)b * 1024 + hd]       + A.pBF[hd];
    float gg = A.gatesW[(size_t)b * 1024 + 512 + hd] + A.pBF[512 + hd];
    float og = A.gatesW[(size_t)b * 1024 + 768 + hd] + A.pBF[768 + hd];
    float c2 = sigf(ig) * tanhf_(gg);      // c_prev = 0
    float h2 = sigf(og) * tanhf_(c2);
    HL[hd] = h2;
    A.haB[b * 256 + hd] = f2bf(h2);
  }
  __syncthreads();
  {
    float acc = A.baF[hd];
#pragma unroll 8
    for (int kk = 0; kk < 256; ++kk) acc += HL[kk] * A.WaF[(size_t)kk * 256 + hd];
    A.aWa[b * 256 + hd] = acc;
  }
  probe_mark(A.bar, 11);
}

// ======================= k_diag =======================
__global__ __launch_bounds__(64) void k_diag(KArgs A) {
  if (threadIdx.x == 0 && blockIdx.x == 0) {
    int bad = -1;
    for (int i = 0; i < NPROBE; ++i) {
      int v = __hip_atomic_load(A.bar + 768 + i, __ATOMIC_ACQUIRE, __HIP_MEMORY_SCOPE_AGENT);
      if (v != PROBE_MAGIC) { bad = i; break; }
    }
    if (bad >= 0) {
      float s = 128.f * (float)(1 << bad);
      for (int j = 0; j < 8; ++j) A.out[j] = s;
    }
  }
}

extern "C" void kernel_launch(void* const* d_in, const int* in_sizes, int n_in,
                              void* d_out, int out_size, void* d_ws, size_t ws_size,
                              hipStream_t stream) {
  (void)in_sizes; (void)n_in; (void)ws_size;
  KArgs A;
  A.pids = (const int*)d_in[0];
  A.qids = (const int*)d_in[1];
  A.plen = (const int*)d_in[2];
  A.qlen = (const int*)d_in[3];
  // d_in[4] = answer (unused)
  A.embedF  = (const float*)d_in[5];
  A.preWihF = (const float*)d_in[6];
  A.preWhhF = (const float*)d_in[7];
  A.preBF   = (const float*)d_in[8];
  A.WqF     = (const float*)d_in[9];
  A.WpF     = (const float*)d_in[10];
  A.bpF     = (const float*)d_in[11];
  A.WhF     = (const float*)d_in[12];
  A.walphaF = (const float*)d_in[13];
  A.balphaF = (const float*)d_in[14];
  A.mWihF   = (const float*)d_in[15];
  A.mWhhF   = (const float*)d_in[16];
  A.mBF     = (const float*)d_in[17];
  A.WmF     = (const float*)d_in[18];
  A.WaF     = (const float*)d_in[19];
  A.baF     = (const float*)d_in[20];
  A.wbetaF  = (const float*)d_in[21];
  A.bbetaF  = (const float*)d_in[22];
  A.pWihF   = (const float*)d_in[23];
  A.pWhhF   = (const float*)d_in[24];
  A.pBF     = (const float*)d_in[25];

  char* w = (char*)d_ws;
  size_t off = 0;
  auto take = [&](size_t bytes) { void* p = w + off; off += (bytes + 255) & ~(size_t)255; return p; };
  A.bar     = (int*)take(4096);
  A.WqT     = (u16*)take(256 * 256 * 2);
  A.WpT     = (u16*)take(256 * 256 * 2);
  A.WmT     = (u16*)take(256 * 512 * 2);
  A.WihP    = (u16*)take((size_t)1024 * 320 * 2);
  A.Xpad    = (u16*)take((size_t)NROWS * 320 * 2);
  A.preX    = (u16*)take((size_t)NROWS * 1024 * 2);
  A.Hp      = (u16*)take((size_t)Pp * Bb * 256 * 2);
  A.Hq      = (u16*)take((size_t)Qq * Bb * 256 * 2);
  A.Hrb     = (u16*)take((size_t)Pp * Bb * 512 * 2);
  A.wqR     = (u16*)take((size_t)Pp * 2 * 32 * 256 * 2);   // 400-deep wq ring
  A.wHr     = (u16*)take(32 * 512 * 2);
  A.haB     = (u16*)take(32 * 256 * 2);
  A.attQb   = (u16*)take((size_t)Qq * Bb * 256 * 2);
  A.pWihB   = (u16*)take((size_t)1024 * 512 * 2);
  A.pWhhB   = (u16*)take((size_t)1024 * 256 * 2);
  A.mWxb    = (u16*)take((size_t)1024 * 256 * 2);
  A.WhTb    = (u16*)take((size_t)256 * 256 * 2);
  A.preWhT  = (u16*)take((size_t)48 * 8 * 512 * 2);
  A.hpWp    = (float*)take((size_t)Pp * Bb * 256 * 4);
  A.attM    = (float*)take((size_t)Pp * Bb * 256 * 4);
  A.scores  = (float*)take((size_t)Pp * Bb * 4);
  A.aWa     = (float*)take(32 * 256 * 4);
  A.gatesW  = (float*)take((size_t)32 * 1024 * 4);
  A.xW      = A.preX;   // alias: preX dead after k_prescan
  A.out     = (float*)d_out;

  hipMemsetAsync(d_out, 0x3C, 64, stream);   // host-alive sentinel
  hipMemsetAsync(A.bar, 0, 4096, stream);    // flags + probes

  (void)hipGetLastError();
  size_t outB = (size_t)out_size * 4;
  int li = 0;
#define CK  if (hipGetLastError() != hipSuccess) { hipMemsetAsync(d_out, 0x41 + li, outB, stream); return; } ++li;

  hipLaunchKernelGGL(k_prep, dim3(256), dim3(256), 0, stream, A); CK;

  GemmArgs g1{A.Xpad, 320, A.WihP, 320, NROWS / 64, 16, 10, nullptr, A.preX, 1024, A.bar, 1};
  hipLaunchKernelGGL(k_gemm, dim3(256), dim3(512), 0, stream, g1); CK;

  hipLaunchKernelGGL(k_prescan, dim3(16), dim3(512), 0, stream, A); CK;

  GemmArgs g2{A.Hq, 256, A.WqT, 256, 20, 4, 8, nullptr, A.attQb, 256, A.bar, 3};
  hipLaunchKernelGGL(k_gemm, dim3(16), dim3(512), 0, stream, g2); CK;
  GemmArgs g3{A.Hp, 256, A.WpT, 256, 200, 4, 8, A.hpWp, nullptr, 256, A.bar, 4};
  hipLaunchKernelGGL(k_gemm, dim3(128), dim3(512), 0, stream, g3); CK;
  GemmArgs gx{A.Hp, 256, A.mWxb, 256, 200, 16, 8, nullptr, A.xW, 1024, A.bar, 5};
  hipLaunchKernelGGL(k_gemm, dim3(256), dim3(512), 0, stream, gx); CK;

  hipLaunchKernelGGL(k_match, dim3(32), dim3(512), 0, stream, A); CK;

  GemmArgs g4{A.Hrb, 512, A.WmT, 512, 200, 4, 16, A.attM, nullptr, 256, A.bar, 7};
  hipLaunchKernelGGL(k_gemm, dim3(128), dim3(512), 0, stream, g4); CK;

  hipLaunchKernelGGL(k_scores, dim3(256), dim3(512), 0, stream, A, 8); CK;
  hipLaunchKernelGGL(k_soft,   dim3(32),  dim3(512), 0, stream, A, 0, 9); CK;
  hipLaunchKernelGGL(k_pgates, dim3(64),  dim3(128), 0, stream, A); CK;
  hipLaunchKernelGGL(k_pcell,  dim3(32),  dim3(256), 0, stream, A); CK;
  hipLaunchKernelGGL(k_scores, dim3(256), dim3(512), 0, stream, A, 12); CK;
  hipLaunchKernelGGL(k_soft,   dim3(32),  dim3(512), 0, stream, A, 1, 13); CK;

  hipLaunchKernelGGL(k_diag,   dim3(1),   dim3(64),  0, stream, A); CK;
#undef CK
}